// Round 1
// baseline (19.470 us; speedup 1.0000x reference)
//
#include <hip/hip_runtime.h>
#include <math.h>

#define CI 16
#define CO 32
#define HH 64
#define WW 64
#define KK 3
#define TH 4
#define TW 16
#define HALO_H (TH + 2)
#define HALO_W (TW + 2)

// RingConv2d: out[b,co,ho,wo] = atan2( sum sin(x_p - w), sum cos(x_p - w) )
// over (ci, kh, kw), zero-padded x (padded positions contribute (cos,sin)=(1,0)
// in the trig domain, i.e. cos(0-w), sin(0-w)).
//
// dir_x = conv(cos x, cos w) + conv(sin x, sin w)
// dir_y = conv(sin x, cos w) - conv(cos x, sin w)

__global__ __launch_bounds__(256)
void RingConv2dSimple_kernel(const float* __restrict__ x,
                             const float* __restrict__ w,
                             float* __restrict__ out) {
    // (cos w, sin w) for all weights: 16*32*9 float2 = 36864 B
    __shared__ float2 wcs[CI * CO * 9];
    // (cos x, sin x) input tile with halo: 16*6*18 float2 = 13824 B
    __shared__ float2 xs[CI][HALO_H][HALO_W];

    const int tid = threadIdx.x;
    const int b   = blockIdx.z;
    const int th0 = blockIdx.y * TH;
    const int tw0 = blockIdx.x * TW;

    // --- stage weight sincos (wave-redundant across blocks, but tiny) ---
    for (int i = tid; i < CI * CO * 9; i += 256) {
        float wv = w[i];                 // flat (ci,co,kh,kw): ci*288+co*9+kh*3+kw
        float s, c;
        __sincosf(wv, &s, &c);
        wcs[i] = make_float2(c, s);
    }

    // --- stage input tile sincos; out-of-bounds (zero-pad) -> (1,0) ---
    for (int i = tid; i < CI * HALO_H * HALO_W; i += 256) {
        int ci  = i / (HALO_H * HALO_W);
        int rem = i - ci * (HALO_H * HALO_W);
        int r   = rem / HALO_W;
        int c   = rem - r * HALO_W;
        int h  = th0 + r - 1;
        int ww = tw0 + c - 1;
        float xv = 0.0f;
        if (h >= 0 && h < HH && ww >= 0 && ww < WW)
            xv = x[((b * CI + ci) * HH + h) * WW + ww];
        float s, c2;
        __sincosf(xv, &s, &c2);          // xv==0 -> (1,0): correct pad value
        xs[ci][r][c] = make_float2(c2, s);
    }
    __syncthreads();

    const int lane = tid & 63;
    const int wid  = tid >> 6;           // 0..3: which block of 8 co's
    const int r    = lane >> 4;          // 0..3  spatial row in tile
    const int c    = lane & 15;          // 0..15 spatial col in tile

    float ax[8], ay[8];
    #pragma unroll
    for (int j = 0; j < 8; ++j) { ax[j] = 0.0f; ay[j] = 0.0f; }

    for (int ci = 0; ci < CI; ++ci) {
        #pragma unroll
        for (int kh = 0; kh < KK; ++kh) {
            #pragma unroll
            for (int kw = 0; kw < KK; ++kw) {
                const float2 p = xs[ci][r + kh][c + kw];     // lane-varying b64
                const float2* wrow = &wcs[(ci * CO + wid * 8) * 9 + kh * 3 + kw];
                #pragma unroll
                for (int j = 0; j < 8; ++j) {
                    const float2 wv = wrow[j * 9];           // wave-uniform (broadcast)
                    ax[j] = fmaf(p.x, wv.x, fmaf(p.y, wv.y, ax[j]));
                    ay[j] = fmaf(p.y, wv.x, fmaf(-p.x, wv.y, ay[j]));
                }
            }
        }
    }

    #pragma unroll
    for (int j = 0; j < 8; ++j) {
        const int co = wid * 8 + j;
        out[((b * CO + co) * HH + (th0 + r)) * WW + (tw0 + c)] =
            atan2f(ay[j], ax[j]);
    }
}

extern "C" void kernel_launch(void* const* d_in, const int* in_sizes, int n_in,
                              void* d_out, int out_size, void* d_ws, size_t ws_size,
                              hipStream_t stream) {
    const float* x = (const float*)d_in[0];   // (B, 16, 64, 64) fp32
    const float* w = (const float*)d_in[1];   // (1, 16, 32, 1, 1, 3, 3) fp32
    float* out = (float*)d_out;               // (B, 32, 64, 64) fp32

    const int B = in_sizes[0] / (CI * HH * WW);
    dim3 grid(WW / TW, HH / TH, B);           // 4 x 16 x B  (=256 blocks for B=4)
    RingConv2dSimple_kernel<<<grid, 256, 0, stream>>>(x, w, out);
}

// Round 2
// 18.918 us; speedup vs baseline: 1.0292x; 1.0292x over previous
//
#include <hip/hip_runtime.h>
#include <math.h>

#define CI 16
#define CO 32
#define HH 64
#define WW 64
#define KK 3
#define TH 4
#define TW 16
#define HALO_H (TH + 2)
#define HALO_W (TW + 2)
#define NTAP 9

// RingConv2d: out[b,co,ho,wo] = atan2( sum sin(x_p - w), sum cos(x_p - w) )
// over (ci,kh,kw), zero-padded x. Padded positions contribute (cos,sin)=(1,0).
// dir_x = conv(cos x, cos w) + conv(sin x, sin w)
// dir_y = conv(sin x, cos w) - conv(cos x, sin w)
//
// Kernel 1 precomputes the weight sincos table into d_ws, laid out per
// co-pair group so the main loop reads 16 B of weights per tap from a
// wave-uniform address (s_load, SGPR operands -> frees LDS + issue slots).
// Layout: wtab[((cg*CI + ci)*NTAP + tap)*4 + col*2 + {0=cos,1=sin}],
// cg = co>>1, col = co&1.

__global__ __launch_bounds__(256)
void ringconv_wprep(const float* __restrict__ w, float* __restrict__ wtab) {
    int i = blockIdx.x * 256 + threadIdx.x;
    if (i >= CI * CO * NTAP) return;
    int ci  = i / (CO * NTAP);
    int rem = i - ci * (CO * NTAP);
    int co  = rem / NTAP;
    int tap = rem - co * NTAP;
    float s, c;
    __sincosf(w[i], &s, &c);
    int cg = co >> 1, col = co & 1;
    float* dst = wtab + (((cg * CI + ci) * NTAP + tap) << 2) + (col << 1);
    dst[0] = c;
    dst[1] = s;
}

__global__ __launch_bounds__(1024)
void ringconv_main(const float* __restrict__ x,
                   const float* __restrict__ wtab,
                   float* __restrict__ out) {
    // (cos x, sin x) input tile with halo: 16*6*18 float2 = 13824 B
    __shared__ float2 xs[CI][HALO_H][HALO_W];

    const int tid = threadIdx.x;
    const int b   = blockIdx.z;
    const int th0 = blockIdx.y * TH;
    const int tw0 = blockIdx.x * TW;

    // --- stage input tile sincos; out-of-bounds (zero-pad) -> (1,0) ---
    for (int i = tid; i < CI * HALO_H * HALO_W; i += 1024) {
        int ci  = i / (HALO_H * HALO_W);
        int rem = i - ci * (HALO_H * HALO_W);
        int rr  = rem / HALO_W;
        int cc  = rem - rr * HALO_W;
        int h  = th0 + rr - 1;
        int ww = tw0 + cc - 1;
        float xv = 0.0f;
        if (h >= 0 && h < HH && ww >= 0 && ww < WW)
            xv = x[((b * CI + ci) * HH + h) * WW + ww];
        float s, c2;
        __sincosf(xv, &s, &c2);          // xv==0 -> (1,0): correct pad value
        xs[ci][rr][cc] = make_float2(c2, s);
    }
    __syncthreads();

    const int lane = tid & 63;
    const int wid  = tid >> 6;                         // 0..15 = co-pair group
    const int cg   = __builtin_amdgcn_readfirstlane(wid);  // force SGPR
    const int r    = lane >> 4;                        // 0..3  spatial row
    const int c    = lane & 15;                        // 0..15 spatial col

    const float* __restrict__ wt = wtab + cg * (CI * NTAP * 4);

    float ax0 = 0.f, ay0 = 0.f, ax1 = 0.f, ay1 = 0.f;

    for (int ci = 0; ci < CI; ++ci) {
        #pragma unroll
        for (int kh = 0; kh < KK; ++kh) {
            #pragma unroll
            for (int kw = 0; kw < KK; ++kw) {
                const float2 p = xs[ci][r + kh][c + kw];   // lane-varying b64
                const float* w4 = wt + ((ci * NTAP + kh * KK + kw) << 2);
                const float wc0 = w4[0], ws0 = w4[1];      // wave-uniform
                const float wc1 = w4[2], ws1 = w4[3];
                ax0 = fmaf(p.x, wc0, fmaf(p.y,  ws0, ax0));
                ay0 = fmaf(p.y, wc0, fmaf(p.x, -ws0, ay0)); // free neg modifier
                ax1 = fmaf(p.x, wc1, fmaf(p.y,  ws1, ax1));
                ay1 = fmaf(p.y, wc1, fmaf(p.x, -ws1, ay1));
            }
        }
    }

    const int co0 = cg * 2;
    const int oidx = ((b * CO + co0) * HH + (th0 + r)) * WW + (tw0 + c);
    out[oidx]           = atan2f(ay0, ax0);
    out[oidx + HH * WW] = atan2f(ay1, ax1);
}

extern "C" void kernel_launch(void* const* d_in, const int* in_sizes, int n_in,
                              void* d_out, int out_size, void* d_ws, size_t ws_size,
                              hipStream_t stream) {
    const float* x = (const float*)d_in[0];   // (B, 16, 64, 64) fp32
    const float* w = (const float*)d_in[1];   // (1, 16, 32, 1, 1, 3, 3) fp32
    float* out  = (float*)d_out;              // (B, 32, 64, 64) fp32
    float* wtab = (float*)d_ws;               // 16*16*9*4 floats = 36 KB

    const int B = in_sizes[0] / (CI * HH * WW);

    ringconv_wprep<<<(CI * CO * NTAP + 255) / 256, 256, 0, stream>>>(w, wtab);

    dim3 grid(WW / TW, HH / TH, B);           // 4 x 16 x 4 = 256 blocks
    ringconv_main<<<grid, 1024, 0, stream>>>(x, wtab, out);
}